// Round 4
// baseline (376.978 us; speedup 1.0000x reference)
//
#include <hip/hip_runtime.h>
#include <math.h>

#define N_PTS 16384
#define K_NBR 16
#define H_DIM 64
#define CAP   80              // per-query/per-part candidate buffer (entries)
#define NBLK  (N_PTS / 16)    // 1024 column-blocks of 16 candidates
#define PBLK  (NBLK / 4)      // 256 column-blocks per wave-part

typedef unsigned long long u64;
typedef unsigned short u16;
typedef float v2f   __attribute__((ext_vector_type(2)));
typedef float f32x4 __attribute__((ext_vector_type(4)));
typedef short bf16x8 __attribute__((ext_vector_type(8)));

// key = (order-preserving float bits, ~idx): sorts by value desc then idx asc
__device__ __forceinline__ u64 mkkey(unsigned vbits, unsigned idx) {
    unsigned of = vbits ^ (unsigned)(((int)vbits >> 31) | 0x80000000);
    return ((u64)of << 32) | (unsigned)(~idx);
}
__device__ __forceinline__ unsigned keyidx(u64 k) { return ~(unsigned)k; }

__device__ __forceinline__ float readlane_f(float v, int l) {
    return __uint_as_float(__builtin_amdgcn_readlane(__float_as_uint(v), l));
}

// order-preserving float<->uint for LDS atomicMax tau sharing
__device__ __forceinline__ unsigned ofsbits(float f) {
    unsigned b = __float_as_uint(f);
    return b ^ ((unsigned)((int)b >> 31) | 0x80000000u);
}
__device__ __forceinline__ float inv_ofs(unsigned u) {
    return __uint_as_float(u ^ (~(unsigned)((int)u >> 31) | 0x80000000u));
}

// bf16 RNE helpers (identical arithmetic in prep and knn query-side)
__device__ __forceinline__ u16 f2bf(float f) {
    unsigned u = __float_as_uint(f);
    return (u16)((u + 0x7FFFu + ((u >> 16) & 1u)) >> 16);
}
__device__ __forceinline__ float bf2f(u16 b) {
    return __uint_as_float(((unsigned)b) << 16);
}

// 64-lane bitonic ascending sort, float
__device__ __forceinline__ float wave_sort_f32(float v, int lane) {
#pragma unroll
    for (int k = 2; k <= 64; k <<= 1) {
#pragma unroll
        for (int j = k >> 1; j > 0; j >>= 1) {
            float o = __shfl_xor(v, j, 64);
            bool keep_min = (((lane & k) == 0) == ((lane & j) == 0));
            v = keep_min ? fminf(v, o) : fmaxf(v, o);
        }
    }
    return v;
}
// 64-lane bitonic ascending sort, u64 keys
__device__ __forceinline__ u64 wave_sort_u64(u64 v, int lane) {
#pragma unroll
    for (int k = 2; k <= 64; k <<= 1) {
#pragma unroll
        for (int j = k >> 1; j > 0; j >>= 1) {
            u64 o = __shfl_xor((unsigned long long)v, j, 64);
            bool keep_min = (((lane & k) == 0) == ((lane & j) == 0));
            u64 mn = (v < o) ? v : o;
            u64 mx = (v < o) ? o : v;
            v = keep_min ? mn : mx;
        }
    }
    return v;
}

// raise tau to 16th-largest of per-lane max VALUES, drop entries below.
// Exact invariant: tau <= 16th-largest value in buffer (>= 16 entries >= tau
// retained; boundary ties kept).
struct CompRes { int nc; float tau; };
__device__ __attribute__((noinline)) CompRes wave_compact(uint2* buf, int cnt,
                                                          int lane) {
    float lm = -INFINITY;
    for (int s = lane; s < cnt; s += 64)
        lm = fmaxf(lm, __uint_as_float(buf[s].x));
    const float tv = readlane_f(wave_sort_f32(lm, lane), 48);
    int nc = 0;
    for (int s0 = 0; s0 < cnt; s0 += 64) {
        const int s = s0 + lane;
        uint2 e = make_uint2(0u, 0u);
        bool keep = false;
        if (s < cnt) { e = buf[s]; keep = (__uint_as_float(e.x) >= tv); }
        const u64 km = __ballot(keep);
        if (keep) {
            int pfx = (int)__popcll(km & ((1ull << lane) - 1));
            buf[nc + pfx] = e;   // write idx <= read idx: safe
        }
        nc += (int)__popcll(km);
    }
    CompRes r; r.nc = nc; r.tau = tv;
    return r;
}

// ---------------- prep: fragment array for bf16x3-split MFMA ---------------
// Score(i,j) = 2*xi.xj - ||xj||^2  (row term -||xi||^2 is rank-invariant).
// K-slot map (k = c + 4p, c=0..3): pairs p:(sa,sb) = (0,0)(0,1)(1,0)(0,2)
// (2,0)(1,1)  [hh,hm,mh,hl,lh,mm of split3]; k=24..26: query-side 1.0,
// cand-side split3(-xx); k=27..31: 0.  Dropped terms (ml,lm,ll) ~2^-27 rel.
// Layout: bfrag[col][32 u16], chunk g (=k/8) at byte col*64 + g*16 so a lane
// fetches its 8 k-values with one dwordx4 load.
__global__ __launch_bounds__(256) void prep_kernel(const float4* __restrict__ x4,
                                                   u16* __restrict__ bf) {
    const int i = blockIdx.x * 256 + threadIdx.x;
    const float4 v = x4[i];
    float xx;
    {
#pragma clang fp contract(off)
        float s0 = v.x * v.x, s1 = v.y * v.y, s2 = v.z * v.z, s3 = v.w * v.w;
        xx = ((s0 + s1) + s2) + s3;
    }
    float c[4] = {v.x, v.y, v.z, v.w};
    u16 H[4], M[4], L[4];
#pragma unroll
    for (int q = 0; q < 4; ++q) {
        float f = c[q];
        u16 h = f2bf(f);            float fh = bf2f(h);
        u16 m = f2bf(f - fh);       float fm = bf2f(m);
        u16 l = f2bf(f - fh - fm);
        H[q] = h; M[q] = m; L[q] = l;
    }
    const float nx = -xx;
    u16 X0 = f2bf(nx);              float x0f = bf2f(X0);
    u16 X1 = f2bf(nx - x0f);        float x1f = bf2f(X1);
    u16 X2 = f2bf(nx - x0f - x1f);
    u16 o[32];
#pragma unroll
    for (int q = 0; q < 4; ++q) {
        o[q]      = H[q];  // p0: sb=hi
        o[4 + q]  = M[q];  // p1: sb=mid
        o[8 + q]  = H[q];  // p2: sb=hi
        o[12 + q] = L[q];  // p3: sb=lo
        o[16 + q] = H[q];  // p4: sb=hi
        o[20 + q] = M[q];  // p5: sb=mid
    }
    o[24] = X0; o[25] = X1; o[26] = X2;
    o[27] = 0; o[28] = 0; o[29] = 0; o[30] = 0; o[31] = 0;
    uint4* dst = (uint4*)(bf + (size_t)i * 32);
#pragma unroll
    for (int q2 = 0; q2 < 4; ++q2) {
        uint4 w;
        w.x = (unsigned)o[q2 * 8 + 0] | ((unsigned)o[q2 * 8 + 1] << 16);
        w.y = (unsigned)o[q2 * 8 + 2] | ((unsigned)o[q2 * 8 + 3] << 16);
        w.z = (unsigned)o[q2 * 8 + 4] | ((unsigned)o[q2 * 8 + 5] << 16);
        w.w = (unsigned)o[q2 * 8 + 6] | ((unsigned)o[q2 * 8 + 7] << 16);
        dst[q2] = w;
    }
}

// ---------------- kNN via transposed MFMA: query = lane&15 -----------------
// R3 post-mortem: rows=queries-across-regs made all per-query bookkeeping
// group-uniform (vector popcll chains, readlane counters) and the loose
// prepass tau flooded ~100 inserts/query. This version SWAPS the MFMA
// operands (both operands share the lane->(index,k-chunk) map, proven by the
// passing R3 kernel): D[m=cand g*4+j][n=query lane&15]. All per-query state
// (tau, count, CAP) is now plain lane-wise vector math, and the 4 waves of a
// block share taus via LDS atomicMax (any compact tv <= p16(part) <=
// p16(global), so shared taus are valid global bounds; uniform >= filtering
// keeps boundary ties, each col visited once -> exact top-16 after merge).
__global__ __launch_bounds__(256, 4) void knn_kernel(
        const float4* __restrict__ x4,
        const u16* __restrict__ bfrag,
        int* __restrict__ knn) {
    __shared__ __align__(16) uint2 buf[4][16][CAP];   // 40 KB
    __shared__ unsigned tau_sh[16];                   // shared tau (ofs bits)
    const int lane = threadIdx.x & 63;
    const int wave = threadIdx.x >> 6;
    const int q    = lane & 15;
    const int g    = lane >> 4;
    const int rowbase = blockIdx.x * 16;
    const int pblk = wave * PBLK;          // part's first 16-col block

    if (threadIdx.x < 16) tau_sh[threadIdx.x] = 0x00800000u;  // ofs(-FLT_MAX)
    __syncthreads();

    // ---- query fragment (B operand): query = q, k-chunk = g ----
    const float4 xi = x4[rowbase + q];
    u16 Ha[4], Ma[4], La[4];
    {
        float yy[4] = {2.f * xi.x, 2.f * xi.y, 2.f * xi.z, 2.f * xi.w};
#pragma unroll
        for (int c = 0; c < 4; ++c) {
            u16 h = f2bf(yy[c]);             float fh = bf2f(h);
            u16 m = f2bf(yy[c] - fh);        float fm = bf2f(m);
            u16 l = f2bf(yy[c] - fh - fm);
            Ha[c] = h; Ma[c] = m; La[c] = l;
        }
    }
    bf16x8 qfrag;
    {
        const u16 ONEB = 0x3F80;  // bf16 1.0
#pragma unroll
        for (int c = 0; c < 4; ++c) {
            u16 lo, hi;
            if (g == 0)      { lo = Ha[c]; hi = Ha[c]; }  // p0:hi  p1:hi
            else if (g == 1) { lo = Ma[c]; hi = Ha[c]; }  // p2:mid p3:hi
            else if (g == 2) { lo = La[c]; hi = Ma[c]; }  // p4:lo  p5:mid
            else             { lo = (c < 3) ? ONEB : 0; hi = 0; }  // k24..26=1
            qfrag[c]     = (short)lo;
            qfrag[c + 4] = (short)hi;
        }
    }
    const f32x4 zacc = {0.f, 0.f, 0.f, 0.f};
    // candidate fragment (A operand): cand-in-block = lane&15, k-chunk = g
    const bf16x8* bp = (const bf16x8*)bfrag + (size_t)pblk * 64 + (q * 4 + g);

    // ---- prepass over part's first 512 cols: per-(g,reg) maxima ----
    // tau = min over 16 distinct candidate-class maxima <= p16(part).
    float tau;
    {
        float mx0 = -INFINITY, mx1 = -INFINITY, mx2 = -INFINITY, mx3 = -INFINITY;
        bf16x8 P[4];
#pragma unroll
        for (int i = 0; i < 4; ++i) P[i] = bp[i * 64];
        for (int t = 0; t < 32; t += 4) {
            bf16x8 Pn[4];
#pragma unroll
            for (int i = 0; i < 4; ++i) {
                int tp = t + 4 + i; if (tp > 31) tp = 31;
                Pn[i] = bp[tp * 64];
            }
            f32x4 aa[4];
#pragma unroll
            for (int i = 0; i < 4; ++i)
                aa[i] = __builtin_amdgcn_mfma_f32_16x16x32_bf16(P[i], qfrag,
                                                                zacc, 0, 0, 0);
#pragma unroll
            for (int i = 0; i < 4; ++i) {
                mx0 = fmaxf(mx0, aa[i][0]);
                mx1 = fmaxf(mx1, aa[i][1]);
                mx2 = fmaxf(mx2, aa[i][2]);
                mx3 = fmaxf(mx3, aa[i][3]);
            }
#pragma unroll
            for (int i = 0; i < 4; ++i) P[i] = Pn[i];
        }
        float m = fminf(fminf(mx0, mx1), fminf(mx2, mx3));
        m = fminf(m, __shfl_xor(m, 16, 64));
        m = fminf(m, __shfl_xor(m, 32, 64));
        tau = m;
        if (lane < 16)   // lanes 0..15 hold q=lane (g=0): publish prepass tau
            atomicMax(&tau_sh[lane], ofsbits(tau));
    }

    unsigned cq = 0;                        // per-query count (lane-wise,
    uint2* bq = &buf[wave][q][0];           //  replicated across the 4 g-lanes)
    const unsigned gid4 = (unsigned)(g * 4);

// lean lane-wise insert; cold path compacts near-full queries (raising taus)
#define INSERT4(AV, CB) do {                                                 \
    for (;;) {                                                               \
        const bool k0 = (AV)[0] >= tau, k1 = (AV)[1] >= tau;                 \
        const bool k2 = (AV)[2] >= tau, k3 = (AV)[3] >= tau;                 \
        const int cnt = (int)k0 + (int)k1 + (int)k2 + (int)k3;               \
        const int sa = __shfl_xor(cnt, 16, 64);                              \
        const int sb = __shfl_xor(cnt, 32, 64);                              \
        const int sc = __shfl_xor(sa, 32, 64);                               \
        const int tot = cnt + sa + sb + sc;                                  \
        const int pf  = ((g & 1) ? sa : 0) + ((g & 2) ? (sb + sc) : 0);      \
        if (__builtin_expect(!__ballot(cq + (unsigned)tot > CAP), 1)) {      \
            unsigned slot = cq + (unsigned)pf;                               \
            if (k0) bq[slot++] = make_uint2(__float_as_uint((AV)[0]), (CB)); \
            if (k1) bq[slot++] = make_uint2(__float_as_uint((AV)[1]), (CB)+1);\
            if (k2) bq[slot++] = make_uint2(__float_as_uint((AV)[2]), (CB)+2);\
            if (k3) bq[slot++] = make_uint2(__float_as_uint((AV)[3]), (CB)+3);\
            cq += (unsigned)tot;                                             \
            break;                                                           \
        }                                                                    \
        for (int r = 0; r < 16; ++r) {   /* rare */                          \
            const unsigned cr =                                              \
                (unsigned)__builtin_amdgcn_readlane((int)cq, r);             \
            if (cr + 16u > CAP) {                                            \
                CompRes res = wave_compact(&buf[wave][r][0], (int)cr, lane); \
                if (q == r) { cq = (unsigned)res.nc;                         \
                              tau = fmaxf(tau, res.tau); }                   \
                if (lane == 0)                                               \
                    atomicMax(&tau_sh[r], ofsbits(res.tau));                 \
            }                                                                \
        }                                                                    \
    }                                                                        \
} while (0)

    // ---- single stream over the whole part, uniform >= (ties kept) ----
    {
        bf16x8 Bc[4], Bn[4];
#pragma unroll
        for (int i = 0; i < 4; ++i) Bc[i] = bp[i * 64];
        for (int t = 0; t < PBLK; t += 4) {
            // pick up block-shared tau (any published value is a valid bound;
            // stale reads are merely looser)
            const unsigned su = __hip_atomic_load(&tau_sh[q], __ATOMIC_RELAXED,
                                                  __HIP_MEMORY_SCOPE_WORKGROUP);
            tau = fmaxf(tau, inv_ofs(su));
#pragma unroll
            for (int i = 0; i < 4; ++i) {
                int tp = t + 4 + i; if (tp >= PBLK) tp = PBLK - 1;
                Bn[i] = bp[tp * 64];
            }
            f32x4 A4[4];
#pragma unroll
            for (int i = 0; i < 4; ++i)
                A4[i] = __builtin_amdgcn_mfma_f32_16x16x32_bf16(Bc[i], qfrag,
                                                                zacc, 0, 0, 0);
#pragma unroll
            for (int i = 0; i < 4; ++i) {
                const f32x4 av = A4[i];
                if (__ballot((av[0] >= tau) | (av[1] >= tau) |
                             (av[2] >= tau) | (av[3] >= tau)))
                    INSERT4(av, (unsigned)((pblk + t + i) * 16) + gid4);
            }
#pragma unroll
            for (int i = 0; i < 4; ++i) Bc[i] = Bn[i];
        }
    }
#undef INSERT4

    // ---- per-part finalize: compact guard, sort, park top-16 keys ----
#pragma unroll 1
    for (int r = 0; r < 16; ++r) {
        int c = __builtin_amdgcn_readlane((int)cq, r);
        uint2* br = &buf[wave][r][0];
        if (c > 64) { CompRes res = wave_compact(br, c, lane); c = res.nc; }
        u64 key = 0;                               // sentinel < any real key
        if (lane < c) { const uint2 e = br[lane]; key = mkkey(e.x, e.y); }
        key = wave_sort_u64(key, lane);
        if (lane >= 48)
            *(u64*)&buf[wave][r][lane - 48] = key;  // part top-16, slots 0..15
    }

    // ---- in-block merge: 64 keys per query (4 disjoint parts x 16) ----
    __syncthreads();
#pragma unroll
    for (int rr = 0; rr < 4; ++rr) {
        const int r2 = wave * 4 + rr;
        u64 key = *(const u64*)&buf[lane >> 4][r2][lane & 15];
        key = wave_sort_u64(key, lane);
        if (lane >= 48)
            knn[(rowbase + r2) * K_NBR + (lane - 48)] = (int)keyidx(key);
    }
}

// ---------------- edge-feature MLP: parallel gather + hoisted W2 -----------
// (unchanged from the proven kernel)
__global__ __launch_bounds__(256, 2) void mlp_kernel(
        const float4* __restrict__ x4,
        const int* __restrict__ knn,
        const float4* __restrict__ W2f4,
        const float* __restrict__ W1,
        const float* __restrict__ b1,
        const float* __restrict__ b2,
        float* __restrict__ out) {
    __shared__ __align__(16) float4 w2s[16][64];     // 16 KB, h4-major
    __shared__ __align__(16) float  h1s[4][32][68];  // 34 KB, per-wave
    __shared__ __align__(16) float4 xjs[4][32];      // 2 KB, per-wave gather
    const int lane = threadIdx.x & 63;
    const int wave = threadIdx.x >> 6;
    const int kq   = lane >> 4;
    const int gp   = lane & 15;
    const int p0   = (blockIdx.x * 4 + wave) * 2;    // 2 points per wave

    for (int q = threadIdx.x; q < 1024; q += 256)
        w2s[q & 15][q >> 4] = W2f4[q];               // w2s[h4][g]
    __syncthreads();

    float w1r[8];
#pragma unroll
    for (int c = 0; c < 8; ++c) w1r[c] = W1[lane * 8 + c];
    const float b1r = b1[lane];
    float b2r[4];
#pragma unroll
    for (int gq = 0; gq < 4; ++gq) b2r[gq] = b2[gq * 16 + gp];

    // parallel gather: 32 indices coalesced, 32 x4 loads in flight at once
    if (lane < 32) {
        const int pp = lane >> 4;
        const int nb = knn[(p0 + pp) * K_NBR + (lane & 15)];
        xjs[wave][lane] = x4[nb];
    }
    // wave-private LDS + in-wave vmcnt/lgkmcnt ordering: no barrier

    // layer 1 for both points (lane = hidden feature h)
#pragma unroll
    for (int pp = 0; pp < 2; ++pp) {
        const float4 xi = x4[p0 + pp];
        float hb = b1r;
        hb = fmaf(w1r[4] - w1r[0], xi.x, hb);
        hb = fmaf(w1r[5] - w1r[1], xi.y, hb);
        hb = fmaf(w1r[6] - w1r[2], xi.z, hb);
        hb = fmaf(w1r[7] - w1r[3], xi.w, hb);
#pragma unroll
        for (int k = 0; k < K_NBR; ++k) {
            const float4 xj = xjs[wave][pp * 16 + k];
            float h = hb;
            h = fmaf(w1r[0], xj.x, h);
            h = fmaf(w1r[1], xj.y, h);
            h = fmaf(w1r[2], xj.z, h);
            h = fmaf(w1r[3], xj.w, h);
            h1s[wave][pp * 16 + k][lane] = fmaxf(h, 0.0f);
        }
    }

    // layer 2: acc[pp][kk][gq] (packed pairs over h), h4-outer, w4 hoisted
    v2f acc[2][4][4];
#pragma unroll
    for (int pp = 0; pp < 2; ++pp)
#pragma unroll
        for (int kk = 0; kk < 4; ++kk)
#pragma unroll
            for (int gq = 0; gq < 4; ++gq)
                acc[pp][kk][gq] = (v2f){b2r[gq], 0.0f};

#pragma unroll
    for (int h4 = 0; h4 < 16; ++h4) {
        float4 w4[4];
#pragma unroll
        for (int gq = 0; gq < 4; ++gq) w4[gq] = w2s[h4][gq * 16 + gp];
#pragma unroll
        for (int pp = 0; pp < 2; ++pp) {
#pragma unroll
            for (int kk = 0; kk < 4; ++kk) {
                const float4 hv =
                    *(const float4*)&h1s[wave][pp * 16 + kq * 4 + kk][h4 * 4];
#pragma unroll
                for (int gq = 0; gq < 4; ++gq) {
                    acc[pp][kk][gq] = __builtin_elementwise_fma(
                        (v2f){hv.x, hv.y}, (v2f){w4[gq].x, w4[gq].y},
                        acc[pp][kk][gq]);
                    acc[pp][kk][gq] = __builtin_elementwise_fma(
                        (v2f){hv.z, hv.w}, (v2f){w4[gq].z, w4[gq].w},
                        acc[pp][kk][gq]);
                }
            }
        }
    }

#pragma unroll
    for (int pp = 0; pp < 2; ++pp) {
        float s[4];
#pragma unroll
        for (int gq = 0; gq < 4; ++gq) {
            s[gq] = 0.0f;
#pragma unroll
            for (int kk = 0; kk < 4; ++kk) {
                const float v = acc[pp][kk][gq].x + acc[pp][kk][gq].y;
                s[gq] += fmaxf(v, 0.0f);
            }
        }
#pragma unroll
        for (int off = 16; off <= 32; off <<= 1)
#pragma unroll
            for (int gq = 0; gq < 4; ++gq)
                s[gq] += __shfl_xor(s[gq], off, 64);

        out[(p0 + pp) * H_DIM + kq * 16 + gp] = s[kq] * (1.0f / 16.0f);
    }
}

extern "C" void kernel_launch(void* const* d_in, const int* in_sizes, int n_in,
                              void* d_out, int out_size, void* d_ws, size_t ws_size,
                              hipStream_t stream) {
    (void)in_sizes; (void)n_in; (void)out_size; (void)ws_size;
    const float* x  = (const float*)d_in[0];
    const float* W1 = (const float*)d_in[1];
    const float* b1 = (const float*)d_in[2];
    const float* W2 = (const float*)d_in[3];
    const float* b2 = (const float*)d_in[4];
    float* out = (float*)d_out;

    int* knn   = (int*)d_ws;                                        // 1 MB
    u16* bfrag = (u16*)((char*)d_ws + (size_t)N_PTS * K_NBR * sizeof(int)); // 1 MB

    const float4* x4 = (const float4*)x;

    prep_kernel<<<N_PTS / 256, 256, 0, stream>>>(x4, bfrag);
    knn_kernel <<<N_PTS / 16,  256, 0, stream>>>(x4, bfrag, knn);
    mlp_kernel <<<N_PTS / 8,   256, 0, stream>>>(
        x4, knn, (const float4*)W2, W1, b1, b2, out);
}

// Round 5
// 280.844 us; speedup vs baseline: 1.3423x; 1.3423x over previous
//
#include <hip/hip_runtime.h>
#include <math.h>

#define N_PTS 16384
#define K_NBR 16
#define H_DIM 64
#define CAP   78              // per-query/per-part buffer; 4*16*CAP*8+64 <= 40960
#define NBLK  (N_PTS / 16)    // 1024 column-blocks of 16 candidates
#define PBLK  (NBLK / 4)      // 256 column-blocks per wave-part

typedef unsigned long long u64;
typedef unsigned short u16;
typedef float v2f   __attribute__((ext_vector_type(2)));
typedef float f32x4 __attribute__((ext_vector_type(4)));
typedef short bf16x8 __attribute__((ext_vector_type(8)));

// key = (order-preserving float bits, ~idx): sorts by value desc then idx asc
__device__ __forceinline__ u64 mkkey(unsigned vbits, unsigned idx) {
    unsigned of = vbits ^ (unsigned)(((int)vbits >> 31) | 0x80000000);
    return ((u64)of << 32) | (unsigned)(~idx);
}
__device__ __forceinline__ unsigned keyidx(u64 k) { return ~(unsigned)k; }

__device__ __forceinline__ float readlane_f(float v, int l) {
    return __uint_as_float(__builtin_amdgcn_readlane(__float_as_uint(v), l));
}

// order-preserving float<->uint for LDS atomicMax tau sharing
__device__ __forceinline__ unsigned ofsbits(float f) {
    unsigned b = __float_as_uint(f);
    return b ^ ((unsigned)((int)b >> 31) | 0x80000000u);
}
__device__ __forceinline__ float inv_ofs(unsigned u) {
    return __uint_as_float(u ^ (~(unsigned)((int)u >> 31) | 0x80000000u));
}

// bf16 RNE helpers (identical arithmetic in prep and knn query-side)
__device__ __forceinline__ u16 f2bf(float f) {
    unsigned u = __float_as_uint(f);
    return (u16)((u + 0x7FFFu + ((u >> 16) & 1u)) >> 16);
}
__device__ __forceinline__ float bf2f(u16 b) {
    return __uint_as_float(((unsigned)b) << 16);
}

// 64-lane bitonic ascending sort, float
__device__ __forceinline__ float wave_sort_f32(float v, int lane) {
#pragma unroll
    for (int k = 2; k <= 64; k <<= 1) {
#pragma unroll
        for (int j = k >> 1; j > 0; j >>= 1) {
            float o = __shfl_xor(v, j, 64);
            bool keep_min = (((lane & k) == 0) == ((lane & j) == 0));
            v = keep_min ? fminf(v, o) : fmaxf(v, o);
        }
    }
    return v;
}
// 64-lane bitonic ascending sort, u64 keys
__device__ __forceinline__ u64 wave_sort_u64(u64 v, int lane) {
#pragma unroll
    for (int k = 2; k <= 64; k <<= 1) {
#pragma unroll
        for (int j = k >> 1; j > 0; j >>= 1) {
            u64 o = __shfl_xor((unsigned long long)v, j, 64);
            bool keep_min = (((lane & k) == 0) == ((lane & j) == 0));
            u64 mn = (v < o) ? v : o;
            u64 mx = (v < o) ? o : v;
            v = keep_min ? mn : mx;
        }
    }
    return v;
}

// raise tau to 16th-largest of per-lane max VALUES, drop entries below.
// Exact invariant: tau <= 16th-largest value in buffer (>= 16 entries >= tau
// retained; boundary ties kept).
struct CompRes { int nc; float tau; };
__device__ __attribute__((noinline)) CompRes wave_compact(uint2* buf, int cnt,
                                                          int lane) {
    float lm = -INFINITY;
    for (int s = lane; s < cnt; s += 64)
        lm = fmaxf(lm, __uint_as_float(buf[s].x));
    const float tv = readlane_f(wave_sort_f32(lm, lane), 48);
    int nc = 0;
    for (int s0 = 0; s0 < cnt; s0 += 64) {
        const int s = s0 + lane;
        uint2 e = make_uint2(0u, 0u);
        bool keep = false;
        if (s < cnt) { e = buf[s]; keep = (__uint_as_float(e.x) >= tv); }
        const u64 km = __ballot(keep);
        if (keep) {
            int pfx = (int)__popcll(km & ((1ull << lane) - 1));
            buf[nc + pfx] = e;   // write idx <= read idx: safe
        }
        nc += (int)__popcll(km);
    }
    CompRes r; r.nc = nc; r.tau = tv;
    return r;
}

// ---------------- prep: fragment array for bf16x3-split MFMA ---------------
// Score(i,j) = 2*xi.xj - ||xj||^2  (row term -||xi||^2 is rank-invariant).
// K-slot map (k = c + 4p, c=0..3): pairs p:(sa,sb) = (0,0)(0,1)(1,0)(0,2)
// (2,0)(1,1)  [hh,hm,mh,hl,lh,mm of split3]; k=24..26: query-side 1.0,
// cand-side split3(-xx); k=27..31: 0.  Dropped terms (ml,lm,ll) ~2^-27 rel.
// Layout: bfrag[col][32 u16], chunk g (=k/8) at byte col*64 + g*16 so a lane
// fetches its 8 k-values with one dwordx4 load.
__global__ __launch_bounds__(256) void prep_kernel(const float4* __restrict__ x4,
                                                   u16* __restrict__ bf) {
    const int i = blockIdx.x * 256 + threadIdx.x;
    const float4 v = x4[i];
    float xx;
    {
#pragma clang fp contract(off)
        float s0 = v.x * v.x, s1 = v.y * v.y, s2 = v.z * v.z, s3 = v.w * v.w;
        xx = ((s0 + s1) + s2) + s3;
    }
    float c[4] = {v.x, v.y, v.z, v.w};
    u16 H[4], M[4], L[4];
#pragma unroll
    for (int q = 0; q < 4; ++q) {
        float f = c[q];
        u16 h = f2bf(f);            float fh = bf2f(h);
        u16 m = f2bf(f - fh);       float fm = bf2f(m);
        u16 l = f2bf(f - fh - fm);
        H[q] = h; M[q] = m; L[q] = l;
    }
    const float nx = -xx;
    u16 X0 = f2bf(nx);              float x0f = bf2f(X0);
    u16 X1 = f2bf(nx - x0f);        float x1f = bf2f(X1);
    u16 X2 = f2bf(nx - x0f - x1f);
    u16 o[32];
#pragma unroll
    for (int q = 0; q < 4; ++q) {
        o[q]      = H[q];  // p0: sb=hi
        o[4 + q]  = M[q];  // p1: sb=mid
        o[8 + q]  = H[q];  // p2: sb=hi
        o[12 + q] = L[q];  // p3: sb=lo
        o[16 + q] = H[q];  // p4: sb=hi
        o[20 + q] = M[q];  // p5: sb=mid
    }
    o[24] = X0; o[25] = X1; o[26] = X2;
    o[27] = 0; o[28] = 0; o[29] = 0; o[30] = 0; o[31] = 0;
    uint4* dst = (uint4*)(bf + (size_t)i * 32);
#pragma unroll
    for (int q2 = 0; q2 < 4; ++q2) {
        uint4 w;
        w.x = (unsigned)o[q2 * 8 + 0] | ((unsigned)o[q2 * 8 + 1] << 16);
        w.y = (unsigned)o[q2 * 8 + 2] | ((unsigned)o[q2 * 8 + 3] << 16);
        w.z = (unsigned)o[q2 * 8 + 4] | ((unsigned)o[q2 * 8 + 5] << 16);
        w.w = (unsigned)o[q2 * 8 + 6] | ((unsigned)o[q2 * 8 + 7] << 16);
        dst[q2] = w;
    }
}

// ---------------- kNN via transposed MFMA: query = lane&15 -----------------
// R4 post-mortem: (a) tau_sh pushed LDS past the exact 4-block/CU boundary
// (4*40960 = 160 KB) -> 3 resident + 256-block tail at 1/CU (occupancy 24%);
// (b) tau only tightened at compacts -> ~100 inserts/query + ~10K inst of
// compact machinery. This version: LDS = 40000 B (CAP=78, tau_sh folded in)
// restoring 4 blk/CU; and CONTINUOUS tau tightening: per-lane running class
// maxima mx[4] (the 16 (g,reg) classes are disjoint cand sets, so min over
// the 16 class-maxima is <= p16(seen) -- same distinct-values proof as the
// prepass), folded into tau every 16 blocks and shared across waves via
// tau_sh atomicMax. Uniform >= filter keeps boundary ties; each col visited
// once -> exact top-16 after the in-block merge.
__global__ __launch_bounds__(256, 4) void knn_kernel(
        const float4* __restrict__ x4,
        const u16* __restrict__ bfrag,
        int* __restrict__ knn) {
    __shared__ __align__(16) uint2 buf[4][16][CAP];   // 39936 B
    __shared__ unsigned tau_sh[16];                   // +64 B = 40000 B
    const int lane = threadIdx.x & 63;
    const int wave = threadIdx.x >> 6;
    const int q    = lane & 15;
    const int g    = lane >> 4;
    const int rowbase = blockIdx.x * 16;
    const int pblk = wave * PBLK;          // part's first 16-col block

    if (threadIdx.x < 16) tau_sh[threadIdx.x] = 0x00800000u;  // ofs(-FLT_MAX)
    __syncthreads();

    // ---- query fragment (B operand): query = q, k-chunk = g ----
    const float4 xi = x4[rowbase + q];
    u16 Ha[4], Ma[4], La[4];
    {
        float yy[4] = {2.f * xi.x, 2.f * xi.y, 2.f * xi.z, 2.f * xi.w};
#pragma unroll
        for (int c = 0; c < 4; ++c) {
            u16 h = f2bf(yy[c]);             float fh = bf2f(h);
            u16 m = f2bf(yy[c] - fh);        float fm = bf2f(m);
            u16 l = f2bf(yy[c] - fh - fm);
            Ha[c] = h; Ma[c] = m; La[c] = l;
        }
    }
    bf16x8 qfrag;
    {
        const u16 ONEB = 0x3F80;  // bf16 1.0
#pragma unroll
        for (int c = 0; c < 4; ++c) {
            u16 lo, hi;
            if (g == 0)      { lo = Ha[c]; hi = Ha[c]; }  // p0:hi  p1:hi
            else if (g == 1) { lo = Ma[c]; hi = Ha[c]; }  // p2:mid p3:hi
            else if (g == 2) { lo = La[c]; hi = Ma[c]; }  // p4:lo  p5:mid
            else             { lo = (c < 3) ? ONEB : 0; hi = 0; }  // k24..26=1
            qfrag[c]     = (short)lo;
            qfrag[c + 4] = (short)hi;
        }
    }
    const f32x4 zacc = {0.f, 0.f, 0.f, 0.f};
    // candidate fragment (A operand): cand-in-block = lane&15, k-chunk = g
    const bf16x8* bp = (const bf16x8*)bfrag + (size_t)pblk * 64 + (q * 4 + g);

    // running class maxima (class = (g, reg j): disjoint candidate sets)
    f32x4 mx = {-INFINITY, -INFINITY, -INFINITY, -INFINITY};

    // ---- prepass over part's first 512 cols: maxima only, no inserts ----
    float tau;
    {
        bf16x8 P[4];
#pragma unroll
        for (int i = 0; i < 4; ++i) P[i] = bp[i * 64];
        for (int t = 0; t < 32; t += 4) {
            bf16x8 Pn[4];
#pragma unroll
            for (int i = 0; i < 4; ++i) {
                int tp = t + 4 + i; if (tp > 31) tp = 31;
                Pn[i] = bp[tp * 64];
            }
#pragma unroll
            for (int i = 0; i < 4; ++i) {
                const f32x4 aa = __builtin_amdgcn_mfma_f32_16x16x32_bf16(
                    P[i], qfrag, zacc, 0, 0, 0);
                mx[0] = fmaxf(mx[0], aa[0]);
                mx[1] = fmaxf(mx[1], aa[1]);
                mx[2] = fmaxf(mx[2], aa[2]);
                mx[3] = fmaxf(mx[3], aa[3]);
            }
#pragma unroll
            for (int i = 0; i < 4; ++i) P[i] = Pn[i];
        }
        float m = fminf(fminf(mx[0], mx[1]), fminf(mx[2], mx[3]));
        m = fminf(m, __shfl_xor(m, 16, 64));
        m = fminf(m, __shfl_xor(m, 32, 64));
        tau = m;   // min of 16 distinct seen values <= p16(seen) <= p16(global)
        if (lane < 16) atomicMax(&tau_sh[lane], ofsbits(tau));
        tau = fmaxf(tau, inv_ofs(__hip_atomic_load(&tau_sh[q], __ATOMIC_RELAXED,
                                                   __HIP_MEMORY_SCOPE_WORKGROUP)));
    }

    unsigned cq = 0;                        // per-query count (lane-wise,
    uint2* bq = &buf[wave][q][0];           //  replicated across the 4 g-lanes)
    const unsigned gid4 = (unsigned)(g * 4);

// lean lane-wise insert; cold path compacts the overflowing queries
// (ballot/ctz-driven), raising their taus and publishing them.
#define INSERT4(AV, CB) do {                                                 \
    for (;;) {                                                               \
        const bool k0 = (AV)[0] >= tau, k1 = (AV)[1] >= tau;                 \
        const bool k2 = (AV)[2] >= tau, k3 = (AV)[3] >= tau;                 \
        const int cnt = (int)k0 + (int)k1 + (int)k2 + (int)k3;               \
        const int sa = __shfl_xor(cnt, 16, 64);                              \
        const int sb = __shfl_xor(cnt, 32, 64);                              \
        const int sc = __shfl_xor(sa, 32, 64);                               \
        const int tot = cnt + sa + sb + sc;                                  \
        const int pf  = ((g & 1) ? sa : 0) + ((g & 2) ? (sb + sc) : 0);      \
        const u64 ovm = __ballot(cq + (unsigned)tot > CAP);                  \
        if (__builtin_expect(ovm == 0, 1)) {                                 \
            unsigned slot = cq + (unsigned)pf;                               \
            if (k0) bq[slot++] = make_uint2(__float_as_uint((AV)[0]), (CB)); \
            if (k1) bq[slot++] = make_uint2(__float_as_uint((AV)[1]), (CB)+1);\
            if (k2) bq[slot++] = make_uint2(__float_as_uint((AV)[2]), (CB)+2);\
            if (k3) bq[slot++] = make_uint2(__float_as_uint((AV)[3]), (CB)+3);\
            cq += (unsigned)tot;                                             \
            break;                                                           \
        }                                                                    \
        u64 ov = ovm & 0xFFFFull;                                            \
        while (ov) {                                                         \
            const int r = (int)__builtin_ctzll(ov); ov &= ov - 1;            \
            const unsigned cr =                                              \
                (unsigned)__builtin_amdgcn_readlane((int)cq, r);             \
            CompRes res = wave_compact(&buf[wave][r][0], (int)cr, lane);     \
            if (q == r) { cq = (unsigned)res.nc;                             \
                          tau = fmaxf(tau, res.tau); }                       \
            if (lane == 0) atomicMax(&tau_sh[r], ofsbits(res.tau));          \
        }                                                                    \
    }                                                                        \
} while (0)

    // ---- single stream over the whole part, uniform >= (ties kept) ----
    {
        bf16x8 Bc[4], Bn[4];
#pragma unroll
        for (int i = 0; i < 4; ++i) Bc[i] = bp[i * 64];
        for (int t = 0; t < PBLK; t += 4) {
#pragma unroll
            for (int i = 0; i < 4; ++i) {
                int tp = t + 4 + i; if (tp >= PBLK) tp = PBLK - 1;
                Bn[i] = bp[tp * 64];
            }
            f32x4 A4[4];
#pragma unroll
            for (int i = 0; i < 4; ++i)
                A4[i] = __builtin_amdgcn_mfma_f32_16x16x32_bf16(Bc[i], qfrag,
                                                                zacc, 0, 0, 0);
#pragma unroll
            for (int i = 0; i < 4; ++i) {
                const f32x4 av = A4[i];
                mx[0] = fmaxf(mx[0], av[0]);
                mx[1] = fmaxf(mx[1], av[1]);
                mx[2] = fmaxf(mx[2], av[2]);
                mx[3] = fmaxf(mx[3], av[3]);
                const float m4 = fmaxf(fmaxf(av[0], av[1]),
                                       fmaxf(av[2], av[3]));
                if (__ballot(m4 >= tau))
                    INSERT4(av, (unsigned)((pblk + t + i) * 16) + gid4);
            }
#pragma unroll
            for (int i = 0; i < 4; ++i) Bc[i] = Bn[i];
            if (((t + 4) & 15) == 0) {     // epoch: tighten + share tau
                float m = fminf(fminf(mx[0], mx[1]), fminf(mx[2], mx[3]));
                m = fminf(m, __shfl_xor(m, 16, 64));
                m = fminf(m, __shfl_xor(m, 32, 64));
                if (lane < 16) atomicMax(&tau_sh[lane], ofsbits(m));
                tau = fmaxf(tau,
                    inv_ofs(__hip_atomic_load(&tau_sh[q], __ATOMIC_RELAXED,
                                              __HIP_MEMORY_SCOPE_WORKGROUP)));
            }
        }
    }
#undef INSERT4

    // ---- per-part finalize: compact guard, sort, park top-16 keys ----
#pragma unroll 1
    for (int r = 0; r < 16; ++r) {
        int c = __builtin_amdgcn_readlane((int)cq, r);
        uint2* br = &buf[wave][r][0];
        if (c > 64) { CompRes res = wave_compact(br, c, lane); c = res.nc; }
        u64 key = 0;                               // sentinel < any real key
        if (lane < c) { const uint2 e = br[lane]; key = mkkey(e.x, e.y); }
        key = wave_sort_u64(key, lane);
        if (lane >= 48)
            *(u64*)&buf[wave][r][lane - 48] = key;  // part top-16, slots 0..15
    }

    // ---- in-block merge: 64 keys per query (4 disjoint parts x 16) ----
    __syncthreads();
#pragma unroll
    for (int rr = 0; rr < 4; ++rr) {
        const int r2 = wave * 4 + rr;
        u64 key = *(const u64*)&buf[lane >> 4][r2][lane & 15];
        key = wave_sort_u64(key, lane);
        if (lane >= 48)
            knn[(rowbase + r2) * K_NBR + (lane - 48)] = (int)keyidx(key);
    }
}

// ---------------- edge-feature MLP: parallel gather + hoisted W2 -----------
// (unchanged from the proven kernel)
__global__ __launch_bounds__(256, 2) void mlp_kernel(
        const float4* __restrict__ x4,
        const int* __restrict__ knn,
        const float4* __restrict__ W2f4,
        const float* __restrict__ W1,
        const float* __restrict__ b1,
        const float* __restrict__ b2,
        float* __restrict__ out) {
    __shared__ __align__(16) float4 w2s[16][64];     // 16 KB, h4-major
    __shared__ __align__(16) float  h1s[4][32][68];  // 34 KB, per-wave
    __shared__ __align__(16) float4 xjs[4][32];      // 2 KB, per-wave gather
    const int lane = threadIdx.x & 63;
    const int wave = threadIdx.x >> 6;
    const int kq   = lane >> 4;
    const int gp   = lane & 15;
    const int p0   = (blockIdx.x * 4 + wave) * 2;    // 2 points per wave

    for (int q = threadIdx.x; q < 1024; q += 256)
        w2s[q & 15][q >> 4] = W2f4[q];               // w2s[h4][g]
    __syncthreads();

    float w1r[8];
#pragma unroll
    for (int c = 0; c < 8; ++c) w1r[c] = W1[lane * 8 + c];
    const float b1r = b1[lane];
    float b2r[4];
#pragma unroll
    for (int gq = 0; gq < 4; ++gq) b2r[gq] = b2[gq * 16 + gp];

    // parallel gather: 32 indices coalesced, 32 x4 loads in flight at once
    if (lane < 32) {
        const int pp = lane >> 4;
        const int nb = knn[(p0 + pp) * K_NBR + (lane & 15)];
        xjs[wave][lane] = x4[nb];
    }
    // wave-private LDS + in-wave vmcnt/lgkmcnt ordering: no barrier

    // layer 1 for both points (lane = hidden feature h)
#pragma unroll
    for (int pp = 0; pp < 2; ++pp) {
        const float4 xi = x4[p0 + pp];
        float hb = b1r;
        hb = fmaf(w1r[4] - w1r[0], xi.x, hb);
        hb = fmaf(w1r[5] - w1r[1], xi.y, hb);
        hb = fmaf(w1r[6] - w1r[2], xi.z, hb);
        hb = fmaf(w1r[7] - w1r[3], xi.w, hb);
#pragma unroll
        for (int k = 0; k < K_NBR; ++k) {
            const float4 xj = xjs[wave][pp * 16 + k];
            float h = hb;
            h = fmaf(w1r[0], xj.x, h);
            h = fmaf(w1r[1], xj.y, h);
            h = fmaf(w1r[2], xj.z, h);
            h = fmaf(w1r[3], xj.w, h);
            h1s[wave][pp * 16 + k][lane] = fmaxf(h, 0.0f);
        }
    }

    // layer 2: acc[pp][kk][gq] (packed pairs over h), h4-outer, w4 hoisted
    v2f acc[2][4][4];
#pragma unroll
    for (int pp = 0; pp < 2; ++pp)
#pragma unroll
        for (int kk = 0; kk < 4; ++kk)
#pragma unroll
            for (int gq = 0; gq < 4; ++gq)
                acc[pp][kk][gq] = (v2f){b2r[gq], 0.0f};

#pragma unroll
    for (int h4 = 0; h4 < 16; ++h4) {
        float4 w4[4];
#pragma unroll
        for (int gq = 0; gq < 4; ++gq) w4[gq] = w2s[h4][gq * 16 + gp];
#pragma unroll
        for (int pp = 0; pp < 2; ++pp) {
#pragma unroll
            for (int kk = 0; kk < 4; ++kk) {
                const float4 hv =
                    *(const float4*)&h1s[wave][pp * 16 + kq * 4 + kk][h4 * 4];
#pragma unroll
                for (int gq = 0; gq < 4; ++gq) {
                    acc[pp][kk][gq] = __builtin_elementwise_fma(
                        (v2f){hv.x, hv.y}, (v2f){w4[gq].x, w4[gq].y},
                        acc[pp][kk][gq]);
                    acc[pp][kk][gq] = __builtin_elementwise_fma(
                        (v2f){hv.z, hv.w}, (v2f){w4[gq].z, w4[gq].w},
                        acc[pp][kk][gq]);
                }
            }
        }
    }

#pragma unroll
    for (int pp = 0; pp < 2; ++pp) {
        float s[4];
#pragma unroll
        for (int gq = 0; gq < 4; ++gq) {
            s[gq] = 0.0f;
#pragma unroll
            for (int kk = 0; kk < 4; ++kk) {
                const float v = acc[pp][kk][gq].x + acc[pp][kk][gq].y;
                s[gq] += fmaxf(v, 0.0f);
            }
        }
#pragma unroll
        for (int off = 16; off <= 32; off <<= 1)
#pragma unroll
            for (int gq = 0; gq < 4; ++gq)
                s[gq] += __shfl_xor(s[gq], off, 64);

        out[(p0 + pp) * H_DIM + kq * 16 + gp] = s[kq] * (1.0f / 16.0f);
    }
}

extern "C" void kernel_launch(void* const* d_in, const int* in_sizes, int n_in,
                              void* d_out, int out_size, void* d_ws, size_t ws_size,
                              hipStream_t stream) {
    (void)in_sizes; (void)n_in; (void)out_size; (void)ws_size;
    const float* x  = (const float*)d_in[0];
    const float* W1 = (const float*)d_in[1];
    const float* b1 = (const float*)d_in[2];
    const float* W2 = (const float*)d_in[3];
    const float* b2 = (const float*)d_in[4];
    float* out = (float*)d_out;

    int* knn   = (int*)d_ws;                                        // 1 MB
    u16* bfrag = (u16*)((char*)d_ws + (size_t)N_PTS * K_NBR * sizeof(int)); // 1 MB

    const float4* x4 = (const float4*)x;

    prep_kernel<<<N_PTS / 256, 256, 0, stream>>>(x4, bfrag);
    knn_kernel <<<N_PTS / 16,  256, 0, stream>>>(x4, bfrag, knn);
    mlp_kernel <<<N_PTS / 8,   256, 0, stream>>>(
        x4, knn, (const float4*)W2, W1, b1, b2, out);
}

// Round 6
// 275.475 us; speedup vs baseline: 1.3685x; 1.0195x over previous
//
#include <hip/hip_runtime.h>
#include <math.h>

#define N_PTS 16384
#define K_NBR 16
#define H_DIM 64
#define CAP   78              // per-query/per-part buffer; 4*16*CAP*8+64 <= 40960
#define NBLK  (N_PTS / 16)    // 1024 column-blocks of 16 candidates
#define PBLK  (NBLK / 4)      // 256 column-blocks per wave-part

typedef unsigned long long u64;
typedef unsigned short u16;
typedef float v2f   __attribute__((ext_vector_type(2)));
typedef float f32x4 __attribute__((ext_vector_type(4)));
typedef short bf16x8 __attribute__((ext_vector_type(8)));

// key = (order-preserving float bits, ~idx): sorts by value desc then idx asc
__device__ __forceinline__ u64 mkkey(unsigned vbits, unsigned idx) {
    unsigned of = vbits ^ (unsigned)(((int)vbits >> 31) | 0x80000000);
    return ((u64)of << 32) | (unsigned)(~idx);
}
__device__ __forceinline__ unsigned keyidx(u64 k) { return ~(unsigned)k; }

__device__ __forceinline__ float readlane_f(float v, int l) {
    return __uint_as_float(__builtin_amdgcn_readlane(__float_as_uint(v), l));
}

// order-preserving float<->uint for LDS atomicMax tau sharing
__device__ __forceinline__ unsigned ofsbits(float f) {
    unsigned b = __float_as_uint(f);
    return b ^ ((unsigned)((int)b >> 31) | 0x80000000u);
}
__device__ __forceinline__ float inv_ofs(unsigned u) {
    return __uint_as_float(u ^ (~(unsigned)((int)u >> 31) | 0x80000000u));
}

// bf16 RNE helpers (identical arithmetic in prep and knn query-side)
__device__ __forceinline__ u16 f2bf(float f) {
    unsigned u = __float_as_uint(f);
    return (u16)((u + 0x7FFFu + ((u >> 16) & 1u)) >> 16);
}
__device__ __forceinline__ float bf2f(u16 b) {
    return __uint_as_float(((unsigned)b) << 16);
}

// 64-lane bitonic ascending sort, float
__device__ __forceinline__ float wave_sort_f32(float v, int lane) {
#pragma unroll
    for (int k = 2; k <= 64; k <<= 1) {
#pragma unroll
        for (int j = k >> 1; j > 0; j >>= 1) {
            float o = __shfl_xor(v, j, 64);
            bool keep_min = (((lane & k) == 0) == ((lane & j) == 0));
            v = keep_min ? fminf(v, o) : fmaxf(v, o);
        }
    }
    return v;
}
// 64-lane bitonic ascending sort, u64 keys
__device__ __forceinline__ u64 wave_sort_u64(u64 v, int lane) {
#pragma unroll
    for (int k = 2; k <= 64; k <<= 1) {
#pragma unroll
        for (int j = k >> 1; j > 0; j >>= 1) {
            u64 o = __shfl_xor((unsigned long long)v, j, 64);
            bool keep_min = (((lane & k) == 0) == ((lane & j) == 0));
            u64 mn = (v < o) ? v : o;
            u64 mx = (v < o) ? o : v;
            v = keep_min ? mn : mx;
        }
    }
    return v;
}

// raise tau to 16th-largest of per-lane max VALUES, drop entries below.
// Exact invariant: tau <= 16th-largest value in buffer (>= 16 entries >= tau
// retained; boundary ties kept).
struct CompRes { int nc; float tau; };
__device__ __attribute__((noinline)) CompRes wave_compact(uint2* buf, int cnt,
                                                          int lane) {
    float lm = -INFINITY;
    for (int s = lane; s < cnt; s += 64)
        lm = fmaxf(lm, __uint_as_float(buf[s].x));
    const float tv = readlane_f(wave_sort_f32(lm, lane), 48);
    int nc = 0;
    for (int s0 = 0; s0 < cnt; s0 += 64) {
        const int s = s0 + lane;
        uint2 e = make_uint2(0u, 0u);
        bool keep = false;
        if (s < cnt) { e = buf[s]; keep = (__uint_as_float(e.x) >= tv); }
        const u64 km = __ballot(keep);
        if (keep) {
            int pfx = (int)__popcll(km & ((1ull << lane) - 1));
            buf[nc + pfx] = e;   // write idx <= read idx: safe
        }
        nc += (int)__popcll(km);
    }
    CompRes r; r.nc = nc; r.tau = tv;
    return r;
}

// ---------------- prep: fragment array for bf16x3-split MFMA ---------------
// Score(i,j) = 2*xi.xj - ||xj||^2  (row term -||xi||^2 is rank-invariant).
// K-slot map (k = c + 4p, c=0..3): pairs p:(sa,sb) = (0,0)(0,1)(1,0)(0,2)
// (2,0)(1,1)  [hh,hm,mh,hl,lh,mm of split3]; k=24..26: query-side 1.0,
// cand-side split3(-xx); k=27..31: 0.  Dropped terms (ml,lm,ll) ~2^-27 rel.
// Layout: bfrag[col][32 u16], chunk g (=k/8) at byte col*64 + g*16 so a lane
// fetches its 8 k-values with one dwordx4 load.
__global__ __launch_bounds__(256) void prep_kernel(const float4* __restrict__ x4,
                                                   u16* __restrict__ bf) {
    const int i = blockIdx.x * 256 + threadIdx.x;
    const float4 v = x4[i];
    float xx;
    {
#pragma clang fp contract(off)
        float s0 = v.x * v.x, s1 = v.y * v.y, s2 = v.z * v.z, s3 = v.w * v.w;
        xx = ((s0 + s1) + s2) + s3;
    }
    float c[4] = {v.x, v.y, v.z, v.w};
    u16 H[4], M[4], L[4];
#pragma unroll
    for (int q = 0; q < 4; ++q) {
        float f = c[q];
        u16 h = f2bf(f);            float fh = bf2f(h);
        u16 m = f2bf(f - fh);       float fm = bf2f(m);
        u16 l = f2bf(f - fh - fm);
        H[q] = h; M[q] = m; L[q] = l;
    }
    const float nx = -xx;
    u16 X0 = f2bf(nx);              float x0f = bf2f(X0);
    u16 X1 = f2bf(nx - x0f);        float x1f = bf2f(X1);
    u16 X2 = f2bf(nx - x0f - x1f);
    u16 o[32];
#pragma unroll
    for (int q = 0; q < 4; ++q) {
        o[q]      = H[q];  // p0: sb=hi
        o[4 + q]  = M[q];  // p1: sb=mid
        o[8 + q]  = H[q];  // p2: sb=hi
        o[12 + q] = L[q];  // p3: sb=lo
        o[16 + q] = H[q];  // p4: sb=hi
        o[20 + q] = M[q];  // p5: sb=mid
    }
    o[24] = X0; o[25] = X1; o[26] = X2;
    o[27] = 0; o[28] = 0; o[29] = 0; o[30] = 0; o[31] = 0;
    uint4* dst = (uint4*)(bf + (size_t)i * 32);
#pragma unroll
    for (int q2 = 0; q2 < 4; ++q2) {
        uint4 w;
        w.x = (unsigned)o[q2 * 8 + 0] | ((unsigned)o[q2 * 8 + 1] << 16);
        w.y = (unsigned)o[q2 * 8 + 2] | ((unsigned)o[q2 * 8 + 3] << 16);
        w.z = (unsigned)o[q2 * 8 + 4] | ((unsigned)o[q2 * 8 + 5] << 16);
        w.w = (unsigned)o[q2 * 8 + 6] | ((unsigned)o[q2 * 8 + 7] << 16);
        dst[q2] = w;
    }
}

// ---------------- kNN via transposed MFMA: query = lane&15 -----------------
// R5 post-mortem: VALUBusy 64% / 40K inst/wave, ~4x the algorithmic floor.
// Bloat was per-tile: Bc=Bn rotation copies (16 movs/4 tiles), re-derived
// load addressing, and full mx updates. This version: copy-free 2-deep
// rotation (manually unrolled x2, two running pointers with immediate
// offsets, tail peeled so refills never read OOB), sampled mx updates
// (every other tile -- classes stay distinct candidate sets, so
// min16(class maxima) <= p16(sampled-seen) remains a valid exact bound).
// Tau machinery, inserts, compacts, finalize are unchanged from R5.
__global__ __launch_bounds__(256, 4) void knn_kernel(
        const float4* __restrict__ x4,
        const u16* __restrict__ bfrag,
        int* __restrict__ knn) {
    __shared__ __align__(16) uint2 buf[4][16][CAP];   // 39936 B
    __shared__ unsigned tau_sh[16];                   // +64 B = 40000 B
    const int lane = threadIdx.x & 63;
    const int wave = threadIdx.x >> 6;
    const int q    = lane & 15;
    const int g    = lane >> 4;
    const int rowbase = blockIdx.x * 16;
    const int pblk = wave * PBLK;          // part's first 16-col block

    if (threadIdx.x < 16) tau_sh[threadIdx.x] = 0x00800000u;  // ofs(-FLT_MAX)
    __syncthreads();

    // ---- query fragment (B operand): query = q, k-chunk = g ----
    const float4 xi = x4[rowbase + q];
    u16 Ha[4], Ma[4], La[4];
    {
        float yy[4] = {2.f * xi.x, 2.f * xi.y, 2.f * xi.z, 2.f * xi.w};
#pragma unroll
        for (int c = 0; c < 4; ++c) {
            u16 h = f2bf(yy[c]);             float fh = bf2f(h);
            u16 m = f2bf(yy[c] - fh);        float fm = bf2f(m);
            u16 l = f2bf(yy[c] - fh - fm);
            Ha[c] = h; Ma[c] = m; La[c] = l;
        }
    }
    bf16x8 qfrag;
    {
        const u16 ONEB = 0x3F80;  // bf16 1.0
#pragma unroll
        for (int c = 0; c < 4; ++c) {
            u16 lo, hi;
            if (g == 0)      { lo = Ha[c]; hi = Ha[c]; }  // p0:hi  p1:hi
            else if (g == 1) { lo = Ma[c]; hi = Ha[c]; }  // p2:mid p3:hi
            else if (g == 2) { lo = La[c]; hi = Ma[c]; }  // p4:lo  p5:mid
            else             { lo = (c < 3) ? ONEB : 0; hi = 0; }  // k24..26=1
            qfrag[c]     = (short)lo;
            qfrag[c + 4] = (short)hi;
        }
    }
    const f32x4 zacc = {0.f, 0.f, 0.f, 0.f};
    // candidate fragment (A operand): cand-in-block = lane&15, k-chunk = g
    const bf16x8* bp = (const bf16x8*)bfrag + (size_t)pblk * 64 + (q * 4 + g);

    // running class maxima (class = (g, reg j): disjoint candidate sets)
    f32x4 mx = {-INFINITY, -INFINITY, -INFINITY, -INFINITY};

    // ---- prepass over part's first 512 cols (blocks 0..31): maxima only ----
    float tau;
    {
        bf16x8 P0[4], P1[4];
#pragma unroll
        for (int i = 0; i < 4; ++i) P0[i] = bp[i * 64];
#pragma unroll
        for (int i = 0; i < 4; ++i) P1[i] = bp[(4 + i) * 64];
        const bf16x8* pp = bp + 8 * 64;

#define PREP4(BUF) do {                                                      \
    _Pragma("unroll")                                                        \
    for (int i = 0; i < 4; ++i) {                                            \
        const f32x4 aa = __builtin_amdgcn_mfma_f32_16x16x32_bf16(            \
            BUF[i], qfrag, zacc, 0, 0, 0);                                   \
        mx[0] = fmaxf(mx[0], aa[0]); mx[1] = fmaxf(mx[1], aa[1]);            \
        mx[2] = fmaxf(mx[2], aa[2]); mx[3] = fmaxf(mx[3], aa[3]);            \
    }                                                                        \
} while (0)

        for (int j = 0; j < 3; ++j) {      // blocks 0..23 with refills
            PREP4(P0);
#pragma unroll
            for (int i = 0; i < 4; ++i) P0[i] = pp[i * 64];
            pp += 4 * 64;
            PREP4(P1);
#pragma unroll
            for (int i = 0; i < 4; ++i) P1[i] = pp[i * 64];
            pp += 4 * 64;
        }
        PREP4(P0);                         // blocks 24..27
        PREP4(P1);                         // blocks 28..31
#undef PREP4

        float m = fminf(fminf(mx[0], mx[1]), fminf(mx[2], mx[3]));
        m = fminf(m, __shfl_xor(m, 16, 64));
        m = fminf(m, __shfl_xor(m, 32, 64));
        tau = m;   // min of 16 distinct seen values <= p16(seen) <= p16(global)
        if (lane < 16) atomicMax(&tau_sh[lane], ofsbits(tau));
        tau = fmaxf(tau, inv_ofs(__hip_atomic_load(&tau_sh[q], __ATOMIC_RELAXED,
                                                   __HIP_MEMORY_SCOPE_WORKGROUP)));
    }

    unsigned cq = 0;                        // per-query count (lane-wise,
    uint2* bq = &buf[wave][q][0];           //  replicated across the 4 g-lanes)
    const unsigned gid4 = (unsigned)(g * 4);

// lean lane-wise insert; cold path compacts the overflowing queries
// (ballot/ctz-driven), raising their taus and publishing them.
#define INSERT4(AV, CB) do {                                                 \
    for (;;) {                                                               \
        const bool k0 = (AV)[0] >= tau, k1 = (AV)[1] >= tau;                 \
        const bool k2 = (AV)[2] >= tau, k3 = (AV)[3] >= tau;                 \
        const int cnt = (int)k0 + (int)k1 + (int)k2 + (int)k3;               \
        const int sa = __shfl_xor(cnt, 16, 64);                              \
        const int sb = __shfl_xor(cnt, 32, 64);                              \
        const int sc = __shfl_xor(sa, 32, 64);                               \
        const int tot = cnt + sa + sb + sc;                                  \
        const int pf  = ((g & 1) ? sa : 0) + ((g & 2) ? (sb + sc) : 0);      \
        const u64 ovm = __ballot(cq + (unsigned)tot > CAP);                  \
        if (__builtin_expect(ovm == 0, 1)) {                                 \
            unsigned slot = cq + (unsigned)pf;                               \
            if (k0) bq[slot++] = make_uint2(__float_as_uint((AV)[0]), (CB)); \
            if (k1) bq[slot++] = make_uint2(__float_as_uint((AV)[1]), (CB)+1);\
            if (k2) bq[slot++] = make_uint2(__float_as_uint((AV)[2]), (CB)+2);\
            if (k3) bq[slot++] = make_uint2(__float_as_uint((AV)[3]), (CB)+3);\
            cq += (unsigned)tot;                                             \
            break;                                                           \
        }                                                                    \
        u64 ov = ovm & 0xFFFFull;                                            \
        while (ov) {                                                         \
            const int r = (int)__builtin_ctzll(ov); ov &= ov - 1;            \
            const unsigned cr =                                              \
                (unsigned)__builtin_amdgcn_readlane((int)cq, r);             \
            CompRes res = wave_compact(&buf[wave][r][0], (int)cr, lane);     \
            if (q == r) { cq = (unsigned)res.nc;                             \
                          tau = fmaxf(tau, res.tau); }                       \
            if (lane == 0) atomicMax(&tau_sh[r], ofsbits(res.tau));          \
        }                                                                    \
    }                                                                        \
} while (0)

// one 16x16 tile: MFMA result -> sampled mx update -> gated insert
#define PROC4(BUF, TB) do {                                                  \
    f32x4 A4_[4];                                                            \
    _Pragma("unroll")                                                        \
    for (int i = 0; i < 4; ++i)                                              \
        A4_[i] = __builtin_amdgcn_mfma_f32_16x16x32_bf16(BUF[i], qfrag,      \
                                                         zacc, 0, 0, 0);     \
    _Pragma("unroll")                                                        \
    for (int i = 0; i < 4; ++i) {                                            \
        const f32x4 av = A4_[i];                                             \
        if ((i & 1) == 0) {                                                  \
            mx[0] = fmaxf(mx[0], av[0]); mx[1] = fmaxf(mx[1], av[1]);        \
            mx[2] = fmaxf(mx[2], av[2]); mx[3] = fmaxf(mx[3], av[3]);        \
        }                                                                    \
        const float m4 = fmaxf(fmaxf(av[0], av[1]), fmaxf(av[2], av[3]));    \
        if (__ballot(m4 >= tau))                                             \
            INSERT4(av, (unsigned)(((TB) + i) * 16) + gid4);                 \
    }                                                                        \
} while (0)

    // ---- main stream over the whole part, uniform >= (ties kept) ----
    // copy-free 2-deep rotation; tail peeled so refills never read OOB
    {
        bf16x8 B0[4], B1[4];
#pragma unroll
        for (int i = 0; i < 4; ++i) B0[i] = bp[i * 64];
#pragma unroll
        for (int i = 0; i < 4; ++i) B1[i] = bp[(4 + i) * 64];
        const bf16x8* pA = bp + 8 * 64;    // refill source for B0 (block t+8)
        const bf16x8* pB = bp + 12 * 64;   // refill source for B1 (block t+12)

        int t = 0;
        for (; t < PBLK - 8; t += 8) {
            PROC4(B0, pblk + t);
#pragma unroll
            for (int i = 0; i < 4; ++i) B0[i] = pA[i * 64];
            pA += 8 * 64;
            PROC4(B1, pblk + t + 4);
#pragma unroll
            for (int i = 0; i < 4; ++i) B1[i] = pB[i * 64];
            pB += 8 * 64;
            if (t & 8) {                   // epoch every 16 blocks
                float m = fminf(fminf(mx[0], mx[1]), fminf(mx[2], mx[3]));
                m = fminf(m, __shfl_xor(m, 16, 64));
                m = fminf(m, __shfl_xor(m, 32, 64));
                if (lane < 16) atomicMax(&tau_sh[lane], ofsbits(m));
                tau = fmaxf(tau,
                    inv_ofs(__hip_atomic_load(&tau_sh[q], __ATOMIC_RELAXED,
                                              __HIP_MEMORY_SCOPE_WORKGROUP)));
            }
        }
        PROC4(B0, pblk + t);               // blocks 248..251
        PROC4(B1, pblk + t + 4);           // blocks 252..255
    }
#undef PROC4
#undef INSERT4

    // ---- per-part finalize: compact guard, sort, park top-16 keys ----
#pragma unroll 1
    for (int r = 0; r < 16; ++r) {
        int c = __builtin_amdgcn_readlane((int)cq, r);
        uint2* br = &buf[wave][r][0];
        if (c > 64) { CompRes res = wave_compact(br, c, lane); c = res.nc; }
        u64 key = 0;                               // sentinel < any real key
        if (lane < c) { const uint2 e = br[lane]; key = mkkey(e.x, e.y); }
        key = wave_sort_u64(key, lane);
        if (lane >= 48)
            *(u64*)&buf[wave][r][lane - 48] = key;  // part top-16, slots 0..15
    }

    // ---- in-block merge: 64 keys per query (4 disjoint parts x 16) ----
    __syncthreads();
#pragma unroll
    for (int rr = 0; rr < 4; ++rr) {
        const int r2 = wave * 4 + rr;
        u64 key = *(const u64*)&buf[lane >> 4][r2][lane & 15];
        key = wave_sort_u64(key, lane);
        if (lane >= 48)
            knn[(rowbase + r2) * K_NBR + (lane - 48)] = (int)keyidx(key);
    }
}

// ---------------- edge-feature MLP: parallel gather + hoisted W2 -----------
// (unchanged from the proven kernel)
__global__ __launch_bounds__(256, 2) void mlp_kernel(
        const float4* __restrict__ x4,
        const int* __restrict__ knn,
        const float4* __restrict__ W2f4,
        const float* __restrict__ W1,
        const float* __restrict__ b1,
        const float* __restrict__ b2,
        float* __restrict__ out) {
    __shared__ __align__(16) float4 w2s[16][64];     // 16 KB, h4-major
    __shared__ __align__(16) float  h1s[4][32][68];  // 34 KB, per-wave
    __shared__ __align__(16) float4 xjs[4][32];      // 2 KB, per-wave gather
    const int lane = threadIdx.x & 63;
    const int wave = threadIdx.x >> 6;
    const int kq   = lane >> 4;
    const int gp   = lane & 15;
    const int p0   = (blockIdx.x * 4 + wave) * 2;    // 2 points per wave

    for (int q = threadIdx.x; q < 1024; q += 256)
        w2s[q & 15][q >> 4] = W2f4[q];               // w2s[h4][g]
    __syncthreads();

    float w1r[8];
#pragma unroll
    for (int c = 0; c < 8; ++c) w1r[c] = W1[lane * 8 + c];
    const float b1r = b1[lane];
    float b2r[4];
#pragma unroll
    for (int gq = 0; gq < 4; ++gq) b2r[gq] = b2[gq * 16 + gp];

    // parallel gather: 32 indices coalesced, 32 x4 loads in flight at once
    if (lane < 32) {
        const int pp = lane >> 4;
        const int nb = knn[(p0 + pp) * K_NBR + (lane & 15)];
        xjs[wave][lane] = x4[nb];
    }
    // wave-private LDS + in-wave vmcnt/lgkmcnt ordering: no barrier

    // layer 1 for both points (lane = hidden feature h)
#pragma unroll
    for (int pp = 0; pp < 2; ++pp) {
        const float4 xi = x4[p0 + pp];
        float hb = b1r;
        hb = fmaf(w1r[4] - w1r[0], xi.x, hb);
        hb = fmaf(w1r[5] - w1r[1], xi.y, hb);
        hb = fmaf(w1r[6] - w1r[2], xi.z, hb);
        hb = fmaf(w1r[7] - w1r[3], xi.w, hb);
#pragma unroll
        for (int k = 0; k < K_NBR; ++k) {
            const float4 xj = xjs[wave][pp * 16 + k];
            float h = hb;
            h = fmaf(w1r[0], xj.x, h);
            h = fmaf(w1r[1], xj.y, h);
            h = fmaf(w1r[2], xj.z, h);
            h = fmaf(w1r[3], xj.w, h);
            h1s[wave][pp * 16 + k][lane] = fmaxf(h, 0.0f);
        }
    }

    // layer 2: acc[pp][kk][gq] (packed pairs over h), h4-outer, w4 hoisted
    v2f acc[2][4][4];
#pragma unroll
    for (int pp = 0; pp < 2; ++pp)
#pragma unroll
        for (int kk = 0; kk < 4; ++kk)
#pragma unroll
            for (int gq = 0; gq < 4; ++gq)
                acc[pp][kk][gq] = (v2f){b2r[gq], 0.0f};

#pragma unroll
    for (int h4 = 0; h4 < 16; ++h4) {
        float4 w4[4];
#pragma unroll
        for (int gq = 0; gq < 4; ++gq) w4[gq] = w2s[h4][gq * 16 + gp];
#pragma unroll
        for (int pp = 0; pp < 2; ++pp) {
#pragma unroll
            for (int kk = 0; kk < 4; ++kk) {
                const float4 hv =
                    *(const float4*)&h1s[wave][pp * 16 + kq * 4 + kk][h4 * 4];
#pragma unroll
                for (int gq = 0; gq < 4; ++gq) {
                    acc[pp][kk][gq] = __builtin_elementwise_fma(
                        (v2f){hv.x, hv.y}, (v2f){w4[gq].x, w4[gq].y},
                        acc[pp][kk][gq]);
                    acc[pp][kk][gq] = __builtin_elementwise_fma(
                        (v2f){hv.z, hv.w}, (v2f){w4[gq].z, w4[gq].w},
                        acc[pp][kk][gq]);
                }
            }
        }
    }

#pragma unroll
    for (int pp = 0; pp < 2; ++pp) {
        float s[4];
#pragma unroll
        for (int gq = 0; gq < 4; ++gq) {
            s[gq] = 0.0f;
#pragma unroll
            for (int kk = 0; kk < 4; ++kk) {
                const float v = acc[pp][kk][gq].x + acc[pp][kk][gq].y;
                s[gq] += fmaxf(v, 0.0f);
            }
        }
#pragma unroll
        for (int off = 16; off <= 32; off <<= 1)
#pragma unroll
            for (int gq = 0; gq < 4; ++gq)
                s[gq] += __shfl_xor(s[gq], off, 64);

        out[(p0 + pp) * H_DIM + kq * 16 + gp] = s[kq] * (1.0f / 16.0f);
    }
}

extern "C" void kernel_launch(void* const* d_in, const int* in_sizes, int n_in,
                              void* d_out, int out_size, void* d_ws, size_t ws_size,
                              hipStream_t stream) {
    (void)in_sizes; (void)n_in; (void)out_size; (void)ws_size;
    const float* x  = (const float*)d_in[0];
    const float* W1 = (const float*)d_in[1];
    const float* b1 = (const float*)d_in[2];
    const float* W2 = (const float*)d_in[3];
    const float* b2 = (const float*)d_in[4];
    float* out = (float*)d_out;

    int* knn   = (int*)d_ws;                                        // 1 MB
    u16* bfrag = (u16*)((char*)d_ws + (size_t)N_PTS * K_NBR * sizeof(int)); // 1 MB

    const float4* x4 = (const float4*)x;

    prep_kernel<<<N_PTS / 256, 256, 0, stream>>>(x4, bfrag);
    knn_kernel <<<N_PTS / 16,  256, 0, stream>>>(x4, bfrag, knn);
    mlp_kernel <<<N_PTS / 8,   256, 0, stream>>>(
        x4, knn, (const float4*)W2, W1, b1, b2, out);
}

// Round 7
// 204.156 us; speedup vs baseline: 1.8465x; 1.3493x over previous
//
#include <hip/hip_runtime.h>
#include <math.h>

#define N_PTS 16384
#define K_NBR 16
#define H_DIM 64
#define CAP   78              // per-query/per-part buffer; 4*16*CAP*8+64 <= 40960
#define NBLK  (N_PTS / 16)    // 1024 column-blocks of 16 candidates
#define PBLK  (NBLK / 4)      // 256 column-blocks per wave-part

typedef unsigned long long u64;
typedef unsigned short u16;
typedef float v2f   __attribute__((ext_vector_type(2)));
typedef float f32x4 __attribute__((ext_vector_type(4)));
typedef short bf16x8 __attribute__((ext_vector_type(8)));

// key = (order-preserving float bits, ~idx): sorts by value desc then idx asc
__device__ __forceinline__ u64 mkkey(unsigned vbits, unsigned idx) {
    unsigned of = vbits ^ (unsigned)(((int)vbits >> 31) | 0x80000000);
    return ((u64)of << 32) | (unsigned)(~idx);
}
__device__ __forceinline__ unsigned keyidx(u64 k) { return ~(unsigned)k; }

__device__ __forceinline__ float readlane_f(float v, int l) {
    return __uint_as_float(__builtin_amdgcn_readlane(__float_as_uint(v), l));
}

// order-preserving float<->uint (tau stored in LDS as monotone uint)
__device__ __forceinline__ unsigned ofsbits(float f) {
    unsigned b = __float_as_uint(f);
    return b ^ ((unsigned)((int)b >> 31) | 0x80000000u);
}
__device__ __forceinline__ float inv_ofs(unsigned u) {
    return __uint_as_float(u ^ (~(unsigned)((int)u >> 31) | 0x80000000u));
}

// bf16 RNE helpers (identical arithmetic in prep and knn query-side)
__device__ __forceinline__ u16 f2bf(float f) {
    unsigned u = __float_as_uint(f);
    return (u16)((u + 0x7FFFu + ((u >> 16) & 1u)) >> 16);
}
__device__ __forceinline__ float bf2f(u16 b) {
    return __uint_as_float(((unsigned)b) << 16);
}

// 64-lane bitonic ascending sort, float
__device__ __forceinline__ float wave_sort_f32(float v, int lane) {
#pragma unroll
    for (int k = 2; k <= 64; k <<= 1) {
#pragma unroll
        for (int j = k >> 1; j > 0; j >>= 1) {
            float o = __shfl_xor(v, j, 64);
            bool keep_min = (((lane & k) == 0) == ((lane & j) == 0));
            v = keep_min ? fminf(v, o) : fmaxf(v, o);
        }
    }
    return v;
}
// 64-lane bitonic ascending sort, u64 keys
__device__ __forceinline__ u64 wave_sort_u64(u64 v, int lane) {
#pragma unroll
    for (int k = 2; k <= 64; k <<= 1) {
#pragma unroll
        for (int j = k >> 1; j > 0; j >>= 1) {
            u64 o = __shfl_xor((unsigned long long)v, j, 64);
            bool keep_min = (((lane & k) == 0) == ((lane & j) == 0));
            u64 mn = (v < o) ? v : o;
            u64 mx = (v < o) ? o : v;
            v = keep_min ? mn : mx;
        }
    }
    return v;
}

// raise tau to 16th-largest of per-lane max VALUES, drop entries below.
// Exact invariant: tau <= 16th-largest value in buffer (>= 16 entries >= tau
// retained; boundary ties kept).
struct CompRes { int nc; float tau; };
__device__ __attribute__((noinline)) CompRes wave_compact(uint2* buf, int cnt,
                                                          int lane) {
    float lm = -INFINITY;
    for (int s = lane; s < cnt; s += 64)
        lm = fmaxf(lm, __uint_as_float(buf[s].x));
    const float tv = readlane_f(wave_sort_f32(lm, lane), 48);
    int nc = 0;
    for (int s0 = 0; s0 < cnt; s0 += 64) {
        const int s = s0 + lane;
        uint2 e = make_uint2(0u, 0u);
        bool keep = false;
        if (s < cnt) { e = buf[s]; keep = (__uint_as_float(e.x) >= tv); }
        const u64 km = __ballot(keep);
        if (keep) {
            int pfx = (int)__popcll(km & ((1ull << lane) - 1));
            buf[nc + pfx] = e;   // write idx <= read idx: safe
        }
        nc += (int)__popcll(km);
    }
    CompRes r; r.nc = nc; r.tau = tv;
    return r;
}

// ---------------- prep: fragment array for bf16x3-split MFMA ---------------
// Score(i,j) = 2*xi.xj - ||xj||^2  (row term -||xi||^2 is rank-invariant).
// K-slot map (k = c + 4p, c=0..3): pairs p:(sa,sb) = (0,0)(0,1)(1,0)(0,2)
// (2,0)(1,1)  [hh,hm,mh,hl,lh,mm of split3]; k=24..26: query-side 1.0,
// cand-side split3(-xx); k=27..31: 0.  Dropped terms (ml,lm,ll) ~2^-27 rel.
// Layout: bfrag[col][32 u16], chunk g (=k/8) at byte col*64 + g*16 so a lane
// fetches its 8 k-values with one dwordx4 load.
__global__ __launch_bounds__(256) void prep_kernel(const float4* __restrict__ x4,
                                                   u16* __restrict__ bf) {
    const int i = blockIdx.x * 256 + threadIdx.x;
    const float4 v = x4[i];
    float xx;
    {
#pragma clang fp contract(off)
        float s0 = v.x * v.x, s1 = v.y * v.y, s2 = v.z * v.z, s3 = v.w * v.w;
        xx = ((s0 + s1) + s2) + s3;
    }
    float c[4] = {v.x, v.y, v.z, v.w};
    u16 H[4], M[4], L[4];
#pragma unroll
    for (int q = 0; q < 4; ++q) {
        float f = c[q];
        u16 h = f2bf(f);            float fh = bf2f(h);
        u16 m = f2bf(f - fh);       float fm = bf2f(m);
        u16 l = f2bf(f - fh - fm);
        H[q] = h; M[q] = m; L[q] = l;
    }
    const float nx = -xx;
    u16 X0 = f2bf(nx);              float x0f = bf2f(X0);
    u16 X1 = f2bf(nx - x0f);        float x1f = bf2f(X1);
    u16 X2 = f2bf(nx - x0f - x1f);
    u16 o[32];
#pragma unroll
    for (int q = 0; q < 4; ++q) {
        o[q]      = H[q];  // p0: sb=hi
        o[4 + q]  = M[q];  // p1: sb=mid
        o[8 + q]  = H[q];  // p2: sb=hi
        o[12 + q] = L[q];  // p3: sb=lo
        o[16 + q] = H[q];  // p4: sb=hi
        o[20 + q] = M[q];  // p5: sb=mid
    }
    o[24] = X0; o[25] = X1; o[26] = X2;
    o[27] = 0; o[28] = 0; o[29] = 0; o[30] = 0; o[31] = 0;
    uint4* dst = (uint4*)(bf + (size_t)i * 32);
#pragma unroll
    for (int q2 = 0; q2 < 4; ++q2) {
        uint4 w;
        w.x = (unsigned)o[q2 * 8 + 0] | ((unsigned)o[q2 * 8 + 1] << 16);
        w.y = (unsigned)o[q2 * 8 + 2] | ((unsigned)o[q2 * 8 + 3] << 16);
        w.z = (unsigned)o[q2 * 8 + 4] | ((unsigned)o[q2 * 8 + 5] << 16);
        w.w = (unsigned)o[q2 * 8 + 6] | ((unsigned)o[q2 * 8 + 7] << 16);
        dst[q2] = w;
    }
}

// ---------------- kNN via transposed MFMA, TWO-PHASE -----------------------
// R6 post-mortem: streaming-tau machinery (loose prepass tau -> ~128 early
// inserts/query/part + repeated noinline compacts + epoch chains) dominated.
// Phase A: maxima-only pass over every OTHER block (no filters/inserts/LDS):
// per (part,g,reg) class maxima -> 64 disjoint-class maxima per query; tau =
// 16th-largest of the 64 (top-16 class maxima are 16 DISTINCT candidates
// >= tau => tau <= p16(global); sampling only loosens, never breaks, the
// bound). Phase B: full stream with FIXED tau, uniform >= (ties kept), rare
// inserts, compact fallback (exact, raises local tau only). Class-maxima
// scratch aliases buf (barrier-separated). LDS 40000 B -> 4 blk/CU.
__global__ __launch_bounds__(256, 4) void knn_kernel(
        const float4* __restrict__ x4,
        const u16* __restrict__ bfrag,
        int* __restrict__ knn) {
    __shared__ __align__(16) uint2 buf[4][16][CAP];   // 39936 B
    __shared__ unsigned tau_sh[16];                   // +64 B = 40000 B
    const int lane = threadIdx.x & 63;
    const int wave = threadIdx.x >> 6;
    const int q    = lane & 15;
    const int g    = lane >> 4;
    const int rowbase = blockIdx.x * 16;
    const int pblk = wave * PBLK;          // part's first 16-col block

    // ---- query fragment (B operand): query = q, k-chunk = g ----
    const float4 xi = x4[rowbase + q];
    u16 Ha[4], Ma[4], La[4];
    {
        float yy[4] = {2.f * xi.x, 2.f * xi.y, 2.f * xi.z, 2.f * xi.w};
#pragma unroll
        for (int c = 0; c < 4; ++c) {
            u16 h = f2bf(yy[c]);             float fh = bf2f(h);
            u16 m = f2bf(yy[c] - fh);        float fm = bf2f(m);
            u16 l = f2bf(yy[c] - fh - fm);
            Ha[c] = h; Ma[c] = m; La[c] = l;
        }
    }
    bf16x8 qfrag;
    {
        const u16 ONEB = 0x3F80;  // bf16 1.0
#pragma unroll
        for (int c = 0; c < 4; ++c) {
            u16 lo, hi;
            if (g == 0)      { lo = Ha[c]; hi = Ha[c]; }  // p0:hi  p1:hi
            else if (g == 1) { lo = Ma[c]; hi = Ha[c]; }  // p2:mid p3:hi
            else if (g == 2) { lo = La[c]; hi = Ma[c]; }  // p4:lo  p5:mid
            else             { lo = (c < 3) ? ONEB : 0; hi = 0; }  // k24..26=1
            qfrag[c]     = (short)lo;
            qfrag[c + 4] = (short)hi;
        }
    }
    const f32x4 zacc = {0.f, 0.f, 0.f, 0.f};
    // candidate fragment (A operand): cand-in-block = lane&15, k-chunk = g
    const bf16x8* bp = (const bf16x8*)bfrag + (size_t)pblk * 64 + (q * 4 + g);

    // ================= Phase A: sampled class-maxima (stride-2 blocks) =====
    f32x4 mx = {-INFINITY, -INFINITY, -INFINITY, -INFINITY};
    {
        bf16x8 A0[4], A1[4];
#pragma unroll
        for (int i = 0; i < 4; ++i) A0[i] = bp[(2 * i) * 64];        // 0,2,4,6
#pragma unroll
        for (int i = 0; i < 4; ++i) A1[i] = bp[(8 + 2 * i) * 64];    // 8..14
        const bf16x8* pa = bp + 16 * 64;

#define PROCA(BUF) do {                                                      \
    _Pragma("unroll")                                                        \
    for (int i = 0; i < 4; ++i) {                                            \
        const f32x4 aa = __builtin_amdgcn_mfma_f32_16x16x32_bf16(            \
            BUF[i], qfrag, zacc, 0, 0, 0);                                   \
        mx[0] = fmaxf(mx[0], aa[0]); mx[1] = fmaxf(mx[1], aa[1]);            \
        mx[2] = fmaxf(mx[2], aa[2]); mx[3] = fmaxf(mx[3], aa[3]);            \
    }                                                                        \
} while (0)

        for (int it = 0; it < 15; ++it) {
            PROCA(A0);
#pragma unroll
            for (int i = 0; i < 4; ++i) A0[i] = pa[(2 * i) * 64];
            PROCA(A1);
#pragma unroll
            for (int i = 0; i < 4; ++i) A1[i] = pa[(8 + 2 * i) * 64];
            pa += 16 * 64;
        }
        PROCA(A0);                         // blocks 240,242,244,246
        PROCA(A1);                         // blocks 248,250,252,254
#undef PROCA
    }

    // ---- combine: 64 class-maxima per query -> tau = 16th largest ----
    {
        float* am = (float*)&buf[0][0][0];          // 4 KB scratch alias
        const int base = wave * 256 + q * 16 + g * 4;
        am[base + 0] = mx[0]; am[base + 1] = mx[1];
        am[base + 2] = mx[2]; am[base + 3] = mx[3];
        __syncthreads();
#pragma unroll
        for (int rr = 0; rr < 4; ++rr) {
            const int r = wave * 4 + rr;
            float v = am[(lane >> 4) * 256 + r * 16 + (lane & 15)];
            v = wave_sort_f32(v, lane);
            if (lane == 48) tau_sh[r] = ofsbits(v);  // 16th largest of 64
        }
        __syncthreads();
    }
    float tau = inv_ofs(tau_sh[q]);        // global-tight, fixed for Phase B

    unsigned cq = 0;                        // per-query count (lane-wise,
    uint2* bq = &buf[wave][q][0];           //  replicated across the 4 g-lanes)
    const unsigned gid4 = (unsigned)(g * 4);

// lean lane-wise insert; cold path compacts the overflowing queries
// (ballot/ctz-driven), raising their LOCAL taus (no cross-wave publish:
// tau is already global-tight).
#define INSERT4(AV, CB) do {                                                 \
    for (;;) {                                                               \
        const bool k0 = (AV)[0] >= tau, k1 = (AV)[1] >= tau;                 \
        const bool k2 = (AV)[2] >= tau, k3 = (AV)[3] >= tau;                 \
        const int cnt = (int)k0 + (int)k1 + (int)k2 + (int)k3;               \
        const int sa = __shfl_xor(cnt, 16, 64);                              \
        const int sb = __shfl_xor(cnt, 32, 64);                              \
        const int sc = __shfl_xor(sa, 32, 64);                               \
        const int tot = cnt + sa + sb + sc;                                  \
        const int pf  = ((g & 1) ? sa : 0) + ((g & 2) ? (sb + sc) : 0);      \
        const u64 ovm = __ballot(cq + (unsigned)tot > CAP);                  \
        if (__builtin_expect(ovm == 0, 1)) {                                 \
            unsigned slot = cq + (unsigned)pf;                               \
            if (k0) bq[slot++] = make_uint2(__float_as_uint((AV)[0]), (CB)); \
            if (k1) bq[slot++] = make_uint2(__float_as_uint((AV)[1]), (CB)+1);\
            if (k2) bq[slot++] = make_uint2(__float_as_uint((AV)[2]), (CB)+2);\
            if (k3) bq[slot++] = make_uint2(__float_as_uint((AV)[3]), (CB)+3);\
            cq += (unsigned)tot;                                             \
            break;                                                           \
        }                                                                    \
        u64 ov = ovm & 0xFFFFull;                                            \
        while (ov) {                                                         \
            const int r = (int)__builtin_ctzll(ov); ov &= ov - 1;            \
            const unsigned cr =                                              \
                (unsigned)__builtin_amdgcn_readlane((int)cq, r);             \
            CompRes res = wave_compact(&buf[wave][r][0], (int)cr, lane);     \
            if (q == r) { cq = (unsigned)res.nc;                             \
                          tau = fmaxf(tau, res.tau); }                       \
        }                                                                    \
    }                                                                        \
} while (0)

// one 16x16 block: MFMA -> 3-fmax gate -> rare insert
#define PROC4(BUF, TB) do {                                                  \
    f32x4 A4_[4];                                                            \
    _Pragma("unroll")                                                        \
    for (int i = 0; i < 4; ++i)                                              \
        A4_[i] = __builtin_amdgcn_mfma_f32_16x16x32_bf16(BUF[i], qfrag,      \
                                                         zacc, 0, 0, 0);     \
    _Pragma("unroll")                                                        \
    for (int i = 0; i < 4; ++i) {                                            \
        const f32x4 av = A4_[i];                                             \
        const float m4 = fmaxf(fmaxf(av[0], av[1]), fmaxf(av[2], av[3]));    \
        if (__ballot(m4 >= tau))                                             \
            INSERT4(av, (unsigned)(((TB) + i) * 16) + gid4);                 \
    }                                                                        \
} while (0)

    // ================= Phase B: full stream, fixed tau =====================
    {
        bf16x8 B0[4], B1[4];
#pragma unroll
        for (int i = 0; i < 4; ++i) B0[i] = bp[i * 64];
#pragma unroll
        for (int i = 0; i < 4; ++i) B1[i] = bp[(4 + i) * 64];
        const bf16x8* pA = bp + 8 * 64;    // refill source for B0 (block t+8)
        const bf16x8* pB = bp + 12 * 64;   // refill source for B1 (block t+12)

        int t = 0;
        for (; t < PBLK - 8; t += 8) {
            PROC4(B0, pblk + t);
#pragma unroll
            for (int i = 0; i < 4; ++i) B0[i] = pA[i * 64];
            pA += 8 * 64;
            PROC4(B1, pblk + t + 4);
#pragma unroll
            for (int i = 0; i < 4; ++i) B1[i] = pB[i * 64];
            pB += 8 * 64;
        }
        PROC4(B0, pblk + t);               // blocks 248..251
        PROC4(B1, pblk + t + 4);           // blocks 252..255
    }
#undef PROC4
#undef INSERT4

    // ---- per-part finalize: park top-16 keys (sort only when c > 16) ----
#pragma unroll 1
    for (int r = 0; r < 16; ++r) {
        int c = __builtin_amdgcn_readlane((int)cq, r);
        uint2* br = &buf[wave][r][0];
        if (c > 64) { CompRes res = wave_compact(br, c, lane); c = res.nc; }
        if (c <= 16) {                     // already <= 16: park unsorted
            if (lane < 16) {
                u64 key = 0;
                if (lane < c) { const uint2 e = br[lane]; key = mkkey(e.x, e.y); }
                *(u64*)&buf[wave][r][lane] = key;
            }
        } else {
            u64 key = 0;                   // sentinel < any real key
            if (lane < c) { const uint2 e = br[lane]; key = mkkey(e.x, e.y); }
            key = wave_sort_u64(key, lane);
            if (lane >= 48)
                *(u64*)&buf[wave][r][lane - 48] = key;  // top-16, slots 0..15
        }
    }

    // ---- in-block merge: 64 keys per query (4 disjoint parts x 16) ----
    __syncthreads();
#pragma unroll
    for (int rr = 0; rr < 4; ++rr) {
        const int r2 = wave * 4 + rr;
        u64 key = *(const u64*)&buf[lane >> 4][r2][lane & 15];
        key = wave_sort_u64(key, lane);
        if (lane >= 48)
            knn[(rowbase + r2) * K_NBR + (lane - 48)] = (int)keyidx(key);
    }
}

// ---------------- edge-feature MLP: parallel gather + hoisted W2 -----------
// (unchanged from the proven kernel)
__global__ __launch_bounds__(256, 2) void mlp_kernel(
        const float4* __restrict__ x4,
        const int* __restrict__ knn,
        const float4* __restrict__ W2f4,
        const float* __restrict__ W1,
        const float* __restrict__ b1,
        const float* __restrict__ b2,
        float* __restrict__ out) {
    __shared__ __align__(16) float4 w2s[16][64];     // 16 KB, h4-major
    __shared__ __align__(16) float  h1s[4][32][68];  // 34 KB, per-wave
    __shared__ __align__(16) float4 xjs[4][32];      // 2 KB, per-wave gather
    const int lane = threadIdx.x & 63;
    const int wave = threadIdx.x >> 6;
    const int kq   = lane >> 4;
    const int gp   = lane & 15;
    const int p0   = (blockIdx.x * 4 + wave) * 2;    // 2 points per wave

    for (int q = threadIdx.x; q < 1024; q += 256)
        w2s[q & 15][q >> 4] = W2f4[q];               // w2s[h4][g]
    __syncthreads();

    float w1r[8];
#pragma unroll
    for (int c = 0; c < 8; ++c) w1r[c] = W1[lane * 8 + c];
    const float b1r = b1[lane];
    float b2r[4];
#pragma unroll
    for (int gq = 0; gq < 4; ++gq) b2r[gq] = b2[gq * 16 + gp];

    // parallel gather: 32 indices coalesced, 32 x4 loads in flight at once
    if (lane < 32) {
        const int pp = lane >> 4;
        const int nb = knn[(p0 + pp) * K_NBR + (lane & 15)];
        xjs[wave][lane] = x4[nb];
    }
    // wave-private LDS + in-wave vmcnt/lgkmcnt ordering: no barrier

    // layer 1 for both points (lane = hidden feature h)
#pragma unroll
    for (int pp = 0; pp < 2; ++pp) {
        const float4 xi = x4[p0 + pp];
        float hb = b1r;
        hb = fmaf(w1r[4] - w1r[0], xi.x, hb);
        hb = fmaf(w1r[5] - w1r[1], xi.y, hb);
        hb = fmaf(w1r[6] - w1r[2], xi.z, hb);
        hb = fmaf(w1r[7] - w1r[3], xi.w, hb);
#pragma unroll
        for (int k = 0; k < K_NBR; ++k) {
            const float4 xj = xjs[wave][pp * 16 + k];
            float h = hb;
            h = fmaf(w1r[0], xj.x, h);
            h = fmaf(w1r[1], xj.y, h);
            h = fmaf(w1r[2], xj.z, h);
            h = fmaf(w1r[3], xj.w, h);
            h1s[wave][pp * 16 + k][lane] = fmaxf(h, 0.0f);
        }
    }

    // layer 2: acc[pp][kk][gq] (packed pairs over h), h4-outer, w4 hoisted
    v2f acc[2][4][4];
#pragma unroll
    for (int pp = 0; pp < 2; ++pp)
#pragma unroll
        for (int kk = 0; kk < 4; ++kk)
#pragma unroll
            for (int gq = 0; gq < 4; ++gq)
                acc[pp][kk][gq] = (v2f){b2r[gq], 0.0f};

#pragma unroll
    for (int h4 = 0; h4 < 16; ++h4) {
        float4 w4[4];
#pragma unroll
        for (int gq = 0; gq < 4; ++gq) w4[gq] = w2s[h4][gq * 16 + gp];
#pragma unroll
        for (int pp = 0; pp < 2; ++pp) {
#pragma unroll
            for (int kk = 0; kk < 4; ++kk) {
                const float4 hv =
                    *(const float4*)&h1s[wave][pp * 16 + kq * 4 + kk][h4 * 4];
#pragma unroll
                for (int gq = 0; gq < 4; ++gq) {
                    acc[pp][kk][gq] = __builtin_elementwise_fma(
                        (v2f){hv.x, hv.y}, (v2f){w4[gq].x, w4[gq].y},
                        acc[pp][kk][gq]);
                    acc[pp][kk][gq] = __builtin_elementwise_fma(
                        (v2f){hv.z, hv.w}, (v2f){w4[gq].z, w4[gq].w},
                        acc[pp][kk][gq]);
                }
            }
        }
    }

#pragma unroll
    for (int pp = 0; pp < 2; ++pp) {
        float s[4];
#pragma unroll
        for (int gq = 0; gq < 4; ++gq) {
            s[gq] = 0.0f;
#pragma unroll
            for (int kk = 0; kk < 4; ++kk) {
                const float v = acc[pp][kk][gq].x + acc[pp][kk][gq].y;
                s[gq] += fmaxf(v, 0.0f);
            }
        }
#pragma unroll
        for (int off = 16; off <= 32; off <<= 1)
#pragma unroll
            for (int gq = 0; gq < 4; ++gq)
                s[gq] += __shfl_xor(s[gq], off, 64);

        out[(p0 + pp) * H_DIM + kq * 16 + gp] = s[kq] * (1.0f / 16.0f);
    }
}

extern "C" void kernel_launch(void* const* d_in, const int* in_sizes, int n_in,
                              void* d_out, int out_size, void* d_ws, size_t ws_size,
                              hipStream_t stream) {
    (void)in_sizes; (void)n_in; (void)out_size; (void)ws_size;
    const float* x  = (const float*)d_in[0];
    const float* W1 = (const float*)d_in[1];
    const float* b1 = (const float*)d_in[2];
    const float* W2 = (const float*)d_in[3];
    const float* b2 = (const float*)d_in[4];
    float* out = (float*)d_out;

    int* knn   = (int*)d_ws;                                        // 1 MB
    u16* bfrag = (u16*)((char*)d_ws + (size_t)N_PTS * K_NBR * sizeof(int)); // 1 MB

    const float4* x4 = (const float4*)x;

    prep_kernel<<<N_PTS / 256, 256, 0, stream>>>(x4, bfrag);
    knn_kernel <<<N_PTS / 16,  256, 0, stream>>>(x4, bfrag, knn);
    mlp_kernel <<<N_PTS / 8,   256, 0, stream>>>(
        x4, knn, (const float4*)W2, W1, b1, b2, out);
}